// Round 4
// baseline (605.525 us; speedup 1.0000x reference)
//
#include <hip/hip_runtime.h>

// GRU4REC v8: short-chain recurrence. B=1024, T=256, D=64, H=128.
// 256 blocks x 256 threads (4 waves), 1 block/CU, 4 rows/block (M-pad 16).
//
// v7 -> v8 (theory: step time ~1270 cy is the serial dependence chain:
// ds_read(h) -> 6-deep MFMA -> act -> write -> barrier -> ds_read -> 4-deep
// -> act -> write -> barrier; throughput pipes are mostly idle):
//  * x-partials (kt=0,1 of aR/aU/aC: 12 MFMA) read A-frags DIRECTLY from
//    the static XT buffer (zero-page for pad rows 4..15) and execute in the
//    LDS-latency shadow after the barrier. h-dependent chains: 6 -> 4 kt.
//    The per-step x-commit copy is gone.
//  * All h-dependent chains split 2x2 (two accumulators + final add):
//    dependent MFMA depth 2 per phase instead of 6/4.
//  * Issue order: ds_read ax (XT), ds_read ah (XA-h), x-MFMAs (lgkmcnt(4)),
//    h-chains (lgkmcnt(0)).
// Exchanges r*h and h stay barriered (2/step) — GRU's algorithmic floor.
// LDS: XT 131072 + XA 6656 + XC 6656 + ZROW 128 = 144512 B.
// MFMA/step/wave = 36 (12 x-part + 16 gate-h + 8 cand-h), same as v7.

#define T_   256
#define D_   64
#define H_   128
#define SROW 208   // halves per A-row (416 B) — proven conflict-free

typedef _Float16 half8_t  __attribute__((ext_vector_type(8)));
typedef _Float16 half4_t  __attribute__((ext_vector_type(4)));
typedef float    floatx4  __attribute__((ext_vector_type(4)));

__device__ __forceinline__ float fast_sigmoid(float x) {
    return __builtin_amdgcn_rcpf(1.f + __expf(-x));   // ~1 ulp, ok vs fp16
}
__device__ __forceinline__ float fast_tanh(float s) {
    s = fminf(fmaxf(s, -15.f), 15.f);
    return 1.f - 2.f * __builtin_amdgcn_rcpf(1.f + __expf(2.f * s));
}

__global__ __launch_bounds__(256, 1) void gru_mfma(
    const int* __restrict__ item_his,          // [1024][256]
    const int* __restrict__ seq_lens,          // [1024]
    const float* __restrict__ emb,             // [1e6][64]
    const float* __restrict__ Wg,              // [192][256]
    const float* __restrict__ bg,              // [256]
    const float* __restrict__ Wc,              // [192][128]
    const float* __restrict__ bc,              // [128]
    float* __restrict__ out)                   // [1024][128] fp32
{
    __shared__ __align__(16) _Float16 XT[T_][4][D_];   // x_t fp16, 128 KiB (static)
    __shared__ __align__(16) _Float16 XA[16][SROW];    // h at cols 64..191
    __shared__ __align__(16) _Float16 XC[16][SROW];    // r*h at cols 0..127
    __shared__ __align__(16) _Float16 ZROW[64];        // zero page for pad rows

    const int tid  = threadIdx.x;
    const int w    = tid >> 6;        // wave 0..3
    const int lane = tid & 63;
    const int row0 = blockIdx.x * 4;

    const int bq = lane >> 4;         // k-quad
    const int bn = lane & 15;         // n within tile / A-row

    // ---- persistent B-fragments: wave w owns N-tiles (2w, 2w+1) ----
    half8_t BG0[2][6], BG1[2][6], BC6[2][6];
    #pragma unroll
    for (int j = 0; j < 2; ++j) {
        const int col = (2 * w + j) * 16 + bn;
        #pragma unroll
        for (int kt = 0; kt < 6; ++kt) {
            half8_t f0, f1, fc;
            #pragma unroll
            for (int i = 0; i < 8; ++i) {
                const int k = kt * 32 + bq * 8 + i;
                f0[i] = (_Float16)Wg[k * 256 + col];
                f1[i] = (_Float16)Wg[k * 256 + 128 + col];
                fc[i] = (_Float16)Wc[k * 128 + col];
            }
            BG0[j][kt] = f0; BG1[j][kt] = f1; BC6[j][kt] = fc;
        }
    }

    float bgR[2], bgU[2], bcC[2];
    #pragma unroll
    for (int j = 0; j < 2; ++j) {
        const int col = (2 * w + j) * 16 + bn;
        bgR[j] = bg[col];
        bgU[j] = bg[128 + col];
        bcC[j] = bc[col];
    }

    int len[4];
    #pragma unroll
    for (int r = 0; r < 4; ++r) len[r] = seq_lens[row0 + r];
    const int maxlen = max(max(len[0], len[1]), max(len[2], len[3]));

    // ---- zero A-buffers + zero page ----
    {
        unsigned* pa = (unsigned*)&XA[0][0];
        unsigned* pc = (unsigned*)&XC[0][0];
        for (int i = tid; i < 16 * SROW / 2; i += 256) { pa[i] = 0u; pc[i] = 0u; }
        if (tid < 32) ((unsigned*)ZROW)[tid] = 0u;
    }

    // ---- prologue gather: XT[t][r][d] <- (f16)emb[item_his[r][t]][d] ----
    {
        const int nq = maxlen << 6;                    // float4 units
        for (int i0 = tid; i0 < nq; i0 += 2048) {
            int id[8];
            #pragma unroll
            for (int b = 0; b < 8; ++b) {
                const int i = i0 + (b << 8);
                if (i < nq) id[b] = item_his[(row0 + ((i >> 4) & 3)) * T_ + (i >> 6)];
            }
            float4 v[8];
            #pragma unroll
            for (int b = 0; b < 8; ++b) {
                const int i = i0 + (b << 8);
                if (i < nq)
                    v[b] = *(const float4*)&emb[(size_t)id[b] * D_ + ((i & 15) << 2)];
            }
            #pragma unroll
            for (int b = 0; b < 8; ++b) {
                const int i = i0 + (b << 8);
                if (i < nq) {
                    half4_t hv;
                    hv[0] = (_Float16)v[b].x; hv[1] = (_Float16)v[b].y;
                    hv[2] = (_Float16)v[b].z; hv[3] = (_Float16)v[b].w;
                    *(half4_t*)&XT[i >> 6][(i >> 4) & 3][(i & 15) << 2] = hv;
                }
            }
        }
    }
    float h[2][4] = {{0.f,0.f,0.f,0.f},{0.f,0.f,0.f,0.f}};
    __syncthreads();

    for (int t = 0; t < maxlen; ++t) {
        // ================= Phase 1: gate =================
        // issue x-frag reads first (consumed at lgkmcnt(4)), then h-frags
        half8_t ax[2];
        {
            const _Float16* p0 = (bn < 4) ? &XT[t][bn][bq * 8]      : &ZROW[bq * 8];
            const _Float16* p1 = (bn < 4) ? &XT[t][bn][32 + bq * 8] : &ZROW[bq * 8];
            ax[0] = *(const half8_t*)p0;
            ax[1] = *(const half8_t*)p1;
        }
        half8_t ah[4];
        #pragma unroll
        for (int kk = 0; kk < 4; ++kk)
            ah[kk] = *(const half8_t*)&XA[bn][64 + kk * 32 + bq * 8];

        // x-partials (bias folded) — fill the LDS latency shadow
        floatx4 aR[2], aU[2], aCx[2];
        #pragma unroll
        for (int j = 0; j < 2; ++j) {
            aR[j]  = (floatx4){bgR[j], bgR[j], bgR[j], bgR[j]};
            aU[j]  = (floatx4){bgU[j], bgU[j], bgU[j], bgU[j]};
            aCx[j] = (floatx4){bcC[j], bcC[j], bcC[j], bcC[j]};
            #pragma unroll
            for (int kt = 0; kt < 2; ++kt) {
                aR[j]  = __builtin_amdgcn_mfma_f32_16x16x32_f16(ax[kt], BG0[j][kt], aR[j],  0, 0, 0);
                aU[j]  = __builtin_amdgcn_mfma_f32_16x16x32_f16(ax[kt], BG1[j][kt], aU[j],  0, 0, 0);
                aCx[j] = __builtin_amdgcn_mfma_f32_16x16x32_f16(ax[kt], BC6[j][kt], aCx[j], 0, 0, 0);
            }
        }
        // h-chains, split 2x2 (dep depth 2); r-gate first (it gates the exchange)
        floatx4 aRb[2], aUb[2];
        #pragma unroll
        for (int j = 0; j < 2; ++j) {
            aR[j]  = __builtin_amdgcn_mfma_f32_16x16x32_f16(ah[0], BG0[j][2], aR[j], 0, 0, 0);
            aRb[j] = __builtin_amdgcn_mfma_f32_16x16x32_f16(ah[1], BG0[j][3],
                         (floatx4){0.f,0.f,0.f,0.f}, 0, 0, 0);
            aR[j]  = __builtin_amdgcn_mfma_f32_16x16x32_f16(ah[2], BG0[j][4], aR[j],  0, 0, 0);
            aRb[j] = __builtin_amdgcn_mfma_f32_16x16x32_f16(ah[3], BG0[j][5], aRb[j], 0, 0, 0);
        }
        if (lane < 16) {
            #pragma unroll
            for (int j = 0; j < 2; ++j)
                #pragma unroll
                for (int r = 0; r < 4; ++r) {
                    const float rg = fast_sigmoid(aR[j][r] + aRb[j][r]);
                    XC[r][(2 * w + j) * 16 + lane] = (_Float16)(rg * h[j][r]);
                }
        }
        // u-gate h-chain after the exchange write (consumed in phase 2)
        #pragma unroll
        for (int j = 0; j < 2; ++j) {
            aU[j]  = __builtin_amdgcn_mfma_f32_16x16x32_f16(ah[0], BG1[j][2], aU[j], 0, 0, 0);
            aUb[j] = __builtin_amdgcn_mfma_f32_16x16x32_f16(ah[1], BG1[j][3],
                         (floatx4){0.f,0.f,0.f,0.f}, 0, 0, 0);
            aU[j]  = __builtin_amdgcn_mfma_f32_16x16x32_f16(ah[2], BG1[j][4], aU[j],  0, 0, 0);
            aUb[j] = __builtin_amdgcn_mfma_f32_16x16x32_f16(ah[3], BG1[j][5], aUb[j], 0, 0, 0);
        }
        __syncthreads();

        // ================= Phase 2: cand + h update =================
        half8_t cf[4];
        #pragma unroll
        for (int kk = 0; kk < 4; ++kk)
            cf[kk] = *(const half8_t*)&XC[bn][kk * 32 + bq * 8];

        floatx4 aC[2] = {aCx[0], aCx[1]}, aCb[2];
        #pragma unroll
        for (int j = 0; j < 2; ++j) {
            aC[j]  = __builtin_amdgcn_mfma_f32_16x16x32_f16(cf[0], BC6[j][2], aC[j], 0, 0, 0);
            aCb[j] = __builtin_amdgcn_mfma_f32_16x16x32_f16(cf[1], BC6[j][3],
                         (floatx4){0.f,0.f,0.f,0.f}, 0, 0, 0);
            aC[j]  = __builtin_amdgcn_mfma_f32_16x16x32_f16(cf[2], BC6[j][4], aC[j],  0, 0, 0);
            aCb[j] = __builtin_amdgcn_mfma_f32_16x16x32_f16(cf[3], BC6[j][5], aCb[j], 0, 0, 0);
        }
        if (lane < 16) {
            #pragma unroll
            for (int j = 0; j < 2; ++j)
                #pragma unroll
                for (int r = 0; r < 4; ++r) {
                    const float ug = fast_sigmoid(aU[j][r] + aUb[j][r]);
                    const float c  = fast_tanh(aC[j][r] + aCb[j][r]);
                    const float hn = c + ug * (h[j][r] - c);
                    if (t < len[r]) h[j][r] = hn;            // copy-through mask
                    XA[r][64 + (2 * w + j) * 16 + lane] = (_Float16)h[j][r];
                }
        }
        __syncthreads();
    }

    // ---- write final h (fp32): wave w covers cols [32w, 32w+32) ----
    if (lane < 16) {
        #pragma unroll
        for (int j = 0; j < 2; ++j)
            #pragma unroll
            for (int r = 0; r < 4; ++r)
                out[(row0 + r) * H_ + (2 * w + j) * 16 + lane] = h[j][r];
    }
}

extern "C" void kernel_launch(void* const* d_in, const int* in_sizes, int n_in,
                              void* d_out, int out_size, void* d_ws, size_t ws_size,
                              hipStream_t stream) {
    const int*   item_his = (const int*)d_in[0];
    const int*   seq_lens = (const int*)d_in[1];
    const float* emb      = (const float*)d_in[2];
    const float* Wg       = (const float*)d_in[3];
    const float* bg       = (const float*)d_in[4];
    const float* Wc       = (const float*)d_in[5];
    const float* bc       = (const float*)d_in[6];
    float*       out      = (float*)d_out;

    gru_mfma<<<256, 256, 0, stream>>>(item_his, seq_lens, emb, Wg, bg, Wc, bc, out);
}